// Round 2
// baseline (712.780 us; speedup 1.0000x reference)
//
#include <hip/hip_runtime.h>

// SelfAttentionBlock: x[8,2048,512]; Wq/Wk/Wv [512,512]; bq/bk/bv [512].
// out[8,2048,1024] = concat(x, causal_softmax(QK^T/sqrt(512)) @ V).
// Input/output dtype (fp32 vs bf16) detected at runtime on-device; all internal
// compute in bf16 MFMA with fp32 accumulation.

#define DEV __device__ __forceinline__

typedef unsigned short u16;
typedef unsigned int u32;
typedef __attribute__((ext_vector_type(8))) short short8;   // 8 bf16 = 4 VGPRs (MFMA A/B frag)
typedef __attribute__((ext_vector_type(4))) float float4v;  // MFMA C/D frag

DEV u16 f2bf(float f) {            // round-to-nearest-even fp32 -> bf16
    u32 u = __float_as_uint(f);
    return (u16)((u + 0x7FFFu + ((u >> 16) & 1u)) >> 16);
}
DEV float bf2f(u16 h) { return __uint_as_float(((u32)h) << 16); }

DEV float4v mfma16(short8 a, short8 b, float4v c) {
    return __builtin_amdgcn_mfma_f32_16x16x32_bf16(a, b, c, 0, 0, 0);
}

// ---------------- Kernel 0: detect input dtype ------------------------------
// bf16 buffer: low u16 of each u32 is a bf16 ~N(0,1) -> exponent in [0x60,0x90]
// nearly always. fp32 buffer: low u16 = mantissa noise -> ~19% in range.
__global__ void detect_k(const u32* __restrict__ xw, int* __restrict__ flag) {
    __shared__ int sh[256];
    int tid = threadIdx.x;
    u32 w = xw[tid * 64];
    int e = (w >> 7) & 0xFF;
    sh[tid] = (e >= 0x60 && e <= 0x90) ? 1 : 0;
    __syncthreads();
    for (int s = 128; s > 0; s >>= 1) {
        if (tid < s) sh[tid] += sh[tid + s];
        __syncthreads();
    }
    if (tid == 0) flag[0] = (sh[0] > 128) ? 1 : 0;   // 1 = bf16 inputs/outputs
}

// ---------------- Kernel 1: canonicalize x to bf16 --------------------------
__global__ void convx_k(const void* __restrict__ x, const int* __restrict__ flag,
                        u16* __restrict__ xb) {
    int i0 = (blockIdx.x * 256 + threadIdx.x) * 8;
    if (flag[0]) {
        *(uint4*)&xb[i0] = *(const uint4*)((const u16*)x + i0);
    } else {
        const float* xf = (const float*)x;
        float4 f0 = *(const float4*)(xf + i0);
        float4 f1 = *(const float4*)(xf + i0 + 4);
        union { u16 us[8]; uint4 v; } pk;
        pk.us[0] = f2bf(f0.x); pk.us[1] = f2bf(f0.y);
        pk.us[2] = f2bf(f0.z); pk.us[3] = f2bf(f0.w);
        pk.us[4] = f2bf(f1.x); pk.us[5] = f2bf(f1.y);
        pk.us[6] = f2bf(f1.z); pk.us[7] = f2bf(f1.w);
        *(uint4*)&xb[i0] = pk.v;
    }
}

// ---------------- Kernel 2: transpose + canonicalize weights ----------------
// Wt[z][n][k] = W_z[k][n] as bf16.
__global__ void convw_k(const void* __restrict__ Wq, const void* __restrict__ Wk,
                        const void* __restrict__ Wv, const int* __restrict__ flag,
                        u16* __restrict__ Wt) {
    int z = blockIdx.y;
    const void* W = (z == 0) ? Wq : ((z == 1) ? Wk : Wv);
    int flat = blockIdx.x * 256 + threadIdx.x;   // = n*512 + k
    int n = flat >> 9, k = flat & 511;
    u16 v = flag[0] ? ((const u16*)W)[k * 512 + n]
                    : f2bf(((const float*)W)[k * 512 + n]);
    Wt[z * 262144 + flat] = v;
}

// ---------------- Kernel 3: canonicalize biases -----------------------------
__global__ void convb_k(const void* __restrict__ bq, const void* __restrict__ bk,
                        const void* __restrict__ bv, const int* __restrict__ flag,
                        u16* __restrict__ bb) {
    int i = blockIdx.x * 256 + threadIdx.x;      // 0..1535
    int z = i >> 9, n = i & 511;
    const void* s = (z == 0) ? bq : ((z == 1) ? bk : bv);
    bb[i] = flag[0] ? ((const u16*)s)[n] : f2bf(((const float*)s)[n]);
}

// ---------------- Kernel 4: copy x into out[..., 0:512] ---------------------
__global__ void xcopy_k(const u16* __restrict__ xb, const int* __restrict__ flag,
                        void* __restrict__ out) {
    int flat = (blockIdx.x * 256 + threadIdx.x) * 8;
    int row = flat >> 9, col = flat & 511;
    uint4 v = *(const uint4*)&xb[flat];
    if (flag[0]) {
        *(uint4*)((u16*)out + (size_t)row * 1024 + col) = v;
    } else {
        const u16* us = (const u16*)&v;
        float* o = (float*)out + (size_t)row * 1024 + col;
        float4 a, b;
        a.x = bf2f(us[0]); a.y = bf2f(us[1]); a.z = bf2f(us[2]); a.w = bf2f(us[3]);
        b.x = bf2f(us[4]); b.y = bf2f(us[5]); b.z = bf2f(us[6]); b.w = bf2f(us[7]);
        *(float4*)o = a; *(float4*)(o + 4) = b;
    }
}

// ---------------- Kernel 5: QKV projection GEMM -----------------------------
// C[16384,512] = xb @ W_z + b_z. 128x128 tile / block, 4 waves 2x2, each wave
// 64x64 = 4x4 MFMA tiles, BK=32. Q,K stored natural [t][d]; V stored transposed
// Vt[b][d][t] so attention's PV B-operand is key-contiguous.
__global__ __launch_bounds__(256) void proj_k(
        const u16* __restrict__ x, const u16* __restrict__ Wt,
        const u16* __restrict__ bb,
        u16* __restrict__ Qo, u16* __restrict__ Ko, u16* __restrict__ Vt_out) {
    int z = blockIdx.z;
    const u16* Wz = Wt + z * 262144;                       // Wz[n][k]
    const u16* bias = bb + z * 512;
    int mBase = blockIdx.x * 128;
    int nBase = blockIdx.y * 128;

    __shared__ __attribute__((aligned(16))) u16 Xs[128 * 32];
    __shared__ __attribute__((aligned(16))) u16 Ws[128 * 32];

    int tid = threadIdx.x;
    int w = tid >> 6, lane = tid & 63, quad = lane >> 4, l16 = lane & 15;
    int wr = (w >> 1) * 64, wc = (w & 1) * 64;

    float4v acc[4][4] = {};                                // [mt][nt]

    for (int k0 = 0; k0 < 512; k0 += 32) {
        int flat0 = tid * 8;
        int row = flat0 >> 5, col = flat0 & 31;
        *(uint4*)&Xs[flat0]        = *(const uint4*)&x [(size_t)(mBase + row)      * 512 + k0 + col];
        *(uint4*)&Xs[flat0 + 2048] = *(const uint4*)&x [(size_t)(mBase + 64 + row) * 512 + k0 + col];
        *(uint4*)&Ws[flat0]        = *(const uint4*)&Wz[(size_t)(nBase + row)      * 512 + k0 + col];
        *(uint4*)&Ws[flat0 + 2048] = *(const uint4*)&Wz[(size_t)(nBase + 64 + row) * 512 + k0 + col];
        __syncthreads();

        short8 a[4], b[4];
        #pragma unroll
        for (int mt = 0; mt < 4; mt++)
            a[mt] = *(const short8*)&Xs[(wr + mt * 16 + l16) * 32 + quad * 8];
        #pragma unroll
        for (int nt = 0; nt < 4; nt++)
            b[nt] = *(const short8*)&Ws[(wc + nt * 16 + l16) * 32 + quad * 8];
        #pragma unroll
        for (int mt = 0; mt < 4; mt++)
            #pragma unroll
            for (int nt = 0; nt < 4; nt++)
                acc[mt][nt] = mfma16(a[mt], b[nt], acc[mt][nt]);
        __syncthreads();
    }

    // epilogue: + bias, cast bf16, store (C/D layout: col=l16, row=quad*4+r)
    #pragma unroll
    for (int nt = 0; nt < 4; nt++) {
        int n = nBase + wc + nt * 16 + l16;
        float bval = bf2f(bias[n]);
        #pragma unroll
        for (int mt = 0; mt < 4; mt++) {
            int m0 = mBase + wr + mt * 16 + quad * 4;
            float4v v = acc[mt][nt];
            if (z == 2) {
                int bbi = m0 >> 11, tt = m0 & 2047;        // Vt[b][d=n][t]
                u16 t0 = f2bf(v[0] + bval), t1 = f2bf(v[1] + bval);
                u16 t2 = f2bf(v[2] + bval), t3 = f2bf(v[3] + bval);
                uint2 pk = make_uint2((u32)t0 | ((u32)t1 << 16), (u32)t2 | ((u32)t3 << 16));
                *(uint2*)&Vt_out[((size_t)bbi * 512 + n) * 2048 + tt] = pk;
            } else {
                u16* dst = (z == 0) ? Qo : Ko;
                #pragma unroll
                for (int r = 0; r < 4; r++)
                    dst[(size_t)(m0 + r) * 512 + n] = f2bf(v[r] + bval);
            }
        }
    }
}

// ---------------- Kernel 6: flash attention (causal, single head) -----------
// Block = 32 q-rows of one batch. 256 threads = 4 waves. K/V tiles of 64 keys,
// D=512 chunked by 128 through a shared 16KB LDS buffer. Online softmax fp32.
__global__ __launch_bounds__(256) void attn_k(
        const u16* __restrict__ Q, const u16* __restrict__ K,
        const u16* __restrict__ Vt, const int* __restrict__ flag,
        void* __restrict__ out) {
    int b = blockIdx.y;
    int qt = gridDim.x - 1 - blockIdx.x;                   // heavy tiles first
    int q0 = qt * 32;
    int isbf = flag[0];

    __shared__ __attribute__((aligned(16))) u16 Qs[32 * 512];    // 32 KB
    __shared__ __attribute__((aligned(16))) u16 KVs[64 * 128];   // 16 KB
    __shared__ __attribute__((aligned(16))) float Ss[32 * 64];   // 8 KB
    __shared__ __attribute__((aligned(16))) u16 Ps[32 * 64];     // 4 KB
    __shared__ float m_s[32], l_s[32], al_s[32];

    int tid = threadIdx.x;
    int w = tid >> 6, lane = tid & 63, quad = lane >> 4, l16 = lane & 15;

    const u16* Qb = Q  + (size_t)b * 2048 * 512;
    const u16* Kb = K  + (size_t)b * 2048 * 512;
    const u16* Vb = Vt + (size_t)b * 512 * 2048;

    #pragma unroll
    for (int rnd = 0; rnd < 8; rnd++) {                    // load Q tile (32x512)
        int flat = rnd * 2048 + tid * 8;
        *(uint4*)&Qs[flat] = *(const uint4*)&Qb[(size_t)(q0 + (flat >> 9)) * 512 + (flat & 511)];
    }
    if (tid < 32) { m_s[tid] = -1e30f; l_s[tid] = 0.0f; }
    float4v accO[4][2][2] = {};                            // [dchunk][dt][mt]
    __syncthreads();

    const float scale = 0.044194173824159216f;             // 1/sqrt(512)
    int nIter = (q0 + 32 + 63) >> 6;

    for (int kt = 0; kt < nIter; kt++) {
        int kBase = kt * 64;

        // ---- S = Q K^T over 4 d-chunks of 128 ----
        float4v accS[2] = {};
        for (int c = 0; c < 4; c++) {
            #pragma unroll
            for (int rnd = 0; rnd < 4; rnd++) {            // stage K chunk [64 keys][128 d]
                int flat = rnd * 2048 + tid * 8;
                int krow = flat >> 7, col = flat & 127;
                *(uint4*)&KVs[flat] = *(const uint4*)&Kb[(size_t)(kBase + krow) * 512 + c * 128 + col];
            }
            __syncthreads();
            #pragma unroll
            for (int kk = 0; kk < 4; kk++) {
                short8 a0 = *(const short8*)&Qs[(l16)      * 512 + c * 128 + kk * 32 + quad * 8];
                short8 a1 = *(const short8*)&Qs[(16 + l16) * 512 + c * 128 + kk * 32 + quad * 8];
                short8 bk = *(const short8*)&KVs[(w * 16 + l16) * 128 + kk * 32 + quad * 8];
                accS[0] = mfma16(a0, bk, accS[0]);
                accS[1] = mfma16(a1, bk, accS[1]);
            }
            __syncthreads();
        }

        // ---- scale + causal mask, spill S to LDS ----
        #pragma unroll
        for (int mt = 0; mt < 2; mt++) {
            int rowg = q0 + mt * 16 + quad * 4;
            int colg = kBase + w * 16 + l16;
            #pragma unroll
            for (int r = 0; r < 4; r++) {
                float s = accS[mt][r] * scale;
                if (colg > rowg + r) s = -1e30f;
                Ss[(mt * 16 + quad * 4 + r) * 64 + w * 16 + l16] = s;
            }
        }
        __syncthreads();

        // ---- online softmax: 8 threads per row ----
        {
            int row = tid >> 3, sg = tid & 7;
            float p[8]; float mx = -1e30f;
            #pragma unroll
            for (int i = 0; i < 8; i++) { p[i] = Ss[row * 64 + sg * 8 + i]; mx = fmaxf(mx, p[i]); }
            #pragma unroll
            for (int off = 1; off < 8; off <<= 1) mx = fmaxf(mx, __shfl_xor(mx, off, 64));
            float mprev = m_s[row];
            float mnew = fmaxf(mprev, mx);
            float sum = 0.0f;
            #pragma unroll
            for (int i = 0; i < 8; i++) { p[i] = __expf(p[i] - mnew); sum += p[i]; }
            #pragma unroll
            for (int off = 1; off < 8; off <<= 1) sum += __shfl_xor(sum, off, 64);
            float alpha = __expf(mprev - mnew);
            if (sg == 0) { m_s[row] = mnew; l_s[row] = l_s[row] * alpha + sum; al_s[row] = alpha; }
            union { u16 us[8]; uint4 v; } pk;
            #pragma unroll
            for (int i = 0; i < 8; i++) pk.us[i] = f2bf(p[i]);
            *(uint4*)&Ps[row * 64 + sg * 8] = pk.v;
        }
        __syncthreads();

        // ---- rescale O, then O += P @ V over 4 d-chunks ----
        float alf[2][4];
        #pragma unroll
        for (int mt = 0; mt < 2; mt++)
            #pragma unroll
            for (int r = 0; r < 4; r++) alf[mt][r] = al_s[mt * 16 + quad * 4 + r];
        #pragma unroll
        for (int c = 0; c < 4; c++)
            #pragma unroll
            for (int dt = 0; dt < 2; dt++)
                #pragma unroll
                for (int mt = 0; mt < 2; mt++)
                    #pragma unroll
                    for (int r = 0; r < 4; r++) accO[c][dt][mt][r] *= alf[mt][r];

        for (int c = 0; c < 4; c++) {
            #pragma unroll
            for (int rnd = 0; rnd < 4; rnd++) {            // stage V chunk [128 d][64 keys]
                int flat = rnd * 2048 + tid * 8;
                int drow = flat >> 6, col = flat & 63;
                *(uint4*)&KVs[flat] = *(const uint4*)&Vb[(size_t)(c * 128 + drow) * 2048 + kBase + col];
            }
            __syncthreads();
            #pragma unroll
            for (int kk = 0; kk < 2; kk++) {
                short8 aP0 = *(const short8*)&Ps[(l16)      * 64 + kk * 32 + quad * 8];
                short8 aP1 = *(const short8*)&Ps[(16 + l16) * 64 + kk * 32 + quad * 8];
                short8 b0 = *(const short8*)&KVs[(w * 32 + l16)      * 64 + kk * 32 + quad * 8];
                short8 b1 = *(const short8*)&KVs[(w * 32 + 16 + l16) * 64 + kk * 32 + quad * 8];
                accO[c][0][0] = mfma16(aP0, b0, accO[c][0][0]);
                accO[c][0][1] = mfma16(aP1, b0, accO[c][0][1]);
                accO[c][1][0] = mfma16(aP0, b1, accO[c][1][0]);
                accO[c][1][1] = mfma16(aP1, b1, accO[c][1][1]);
            }
            __syncthreads();
        }
    }

    // ---- epilogue: O /= l, write out[..., 512:1024] ----
    float invl[2][4];
    #pragma unroll
    for (int mt = 0; mt < 2; mt++)
        #pragma unroll
        for (int r = 0; r < 4; r++) invl[mt][r] = 1.0f / l_s[mt * 16 + quad * 4 + r];
    u16*   o16 = (u16*)out;
    float* o32 = (float*)out;
    #pragma unroll
    for (int c = 0; c < 4; c++)
        #pragma unroll
        for (int dt = 0; dt < 2; dt++)
            #pragma unroll
            for (int mt = 0; mt < 2; mt++) {
                int dg = 512 + c * 128 + w * 32 + dt * 16 + l16;
                #pragma unroll
                for (int r = 0; r < 4; r++) {
                    int rowg = q0 + mt * 16 + quad * 4 + r;
                    size_t idx = ((size_t)b * 2048 + rowg) * 1024 + dg;
                    float val = accO[c][dt][mt][r] * invl[mt][r];
                    if (isbf) o16[idx] = f2bf(val);
                    else      o32[idx] = val;
                }
            }
}

// ---------------- launcher --------------------------------------------------
extern "C" void kernel_launch(void* const* d_in, const int* in_sizes, int n_in,
                              void* d_out, int out_size, void* d_ws, size_t ws_size,
                              hipStream_t stream) {
    const void* x  = d_in[0];
    const void* Wq = d_in[1];
    const void* bq = d_in[2];
    const void* Wk = d_in[3];
    const void* bk = d_in[4];
    const void* Wv = d_in[5];
    const void* bv = d_in[6];

    u16* base = (u16*)d_ws;
    int* flag = (int*)base;                         // 16 B
    u16* Wt   = base + 8;                           // 3*512*512 = 786432
    u16* bb   = Wt + 786432;                        // 1536 (pad to 1544)
    u16* xb   = bb + 1544;                          // 8,388,608
    u16* Qw   = xb + 8388608;
    u16* Kw   = Qw + 8388608;
    u16* Vtw  = Kw + 8388608;                       // total ~68.7 MB

    hipLaunchKernelGGL(detect_k, dim3(1), dim3(256), 0, stream, (const u32*)x, flag);
    hipLaunchKernelGGL(convx_k, dim3(4096), dim3(256), 0, stream, x, flag, xb);
    hipLaunchKernelGGL(convw_k, dim3(1024, 3), dim3(256), 0, stream, Wq, Wk, Wv, flag, Wt);
    hipLaunchKernelGGL(convb_k, dim3(6), dim3(256), 0, stream, bq, bk, bv, flag, bb);
    hipLaunchKernelGGL(xcopy_k, dim3(4096), dim3(256), 0, stream, xb, flag, d_out);
    hipLaunchKernelGGL(proj_k, dim3(128, 4, 3), dim3(256), 0, stream, xb, Wt, bb, Qw, Kw, Vtw);
    hipLaunchKernelGGL(attn_k, dim3(64, 8), dim3(256), 0, stream, Qw, Kw, Vtw, flag, d_out);
}